// Round 4
// baseline (893.027 us; speedup 1.0000x reference)
//
#include <hip/hip_runtime.h>

// Event voxelization (QuantizationLayerBinary):
//   events [N,4] float32 rows (x, y, t, p) -> vox[2*C*H*W] set-to-1.0 scatter.
//   C=16, H=260, W=346. bin = ceil(t*C)-1, p in {-1,1} -> {0,1}.
//
// R1: float scatter into 11.5 MB out -> 548 MB HBM writes.
// R2: byte flags (2.88 MB) -> 788 MB (event read stream evicts dirty lines).
// R3: nt loads only -18% (644 MB): store target can't stay L2-resident vs the
//     32 MB/XCD read stream. Fix: 360 KiB BITMASK + atomicOr (executes at
//     cache, tiny residency footprint), with a read-check to skip ~85% of
//     atomics (bit already set; race-benign).

#define CBINS 16
#define HDIM  260
#define WDIM  346
#define NVOX  (2 * CBINS * HDIM * WDIM)   // 2,878,720
#define NWORDS (NVOX / 32)                // 89,960 u32 words (360 KiB)

typedef float fvec4 __attribute__((ext_vector_type(4)));

__global__ __launch_bounds__(256) void scatter_bits(const fvec4* __restrict__ ev,
                                                    unsigned int* __restrict__ bits,
                                                    int n) {
    int i = blockIdx.x * blockDim.x + threadIdx.x;
    if (i >= n) return;
    fvec4 e = __builtin_nontemporal_load(&ev[i]);   // x,y,t,p — streaming, no reuse
    float t = e.z;
    if (t > 0.f && t <= 1.f) {
        int xi  = (int)e.x;
        int yi  = (int)e.y;
        int pi  = (e.w > 0.f) ? 1 : 0;     // (p_raw+1)*0.5 with p_raw in {-1,1}
        int bin = (int)ceilf(t * (float)CBINS) - 1;   // in [0,15] given valid t
        int idx = xi + WDIM * yi + WDIM * HDIM * (bin + CBINS * pi);
        unsigned int w   = (unsigned int)idx >> 5;
        unsigned int msk = 1u << (idx & 31);
        // check-before-atomic: ~85% of events hit an already-set bit (λ≈5.6).
        // Race-benign: stale read just means a redundant atomicOr.
        if (!(bits[w] & msk)) atomicOr(&bits[w], msk);
    }
}

// Decode 4 bits -> one float4 nt store. Thread i covers voxels [4i, 4i+4).
__global__ __launch_bounds__(256) void expand_bits(const unsigned int* __restrict__ bits,
                                                   fvec4* __restrict__ out, int n4) {
    int i = blockIdx.x * blockDim.x + threadIdx.x;
    if (i >= n4) return;
    unsigned int word = bits[i >> 3];               // 8 threads share a word (L1 hit)
    unsigned int nib  = (word >> ((i & 7) * 4)) & 0xFu;
    fvec4 v = { (nib & 1u) ? 1.f : 0.f, (nib & 2u) ? 1.f : 0.f,
                (nib & 4u) ? 1.f : 0.f, (nib & 8u) ? 1.f : 0.f };
    __builtin_nontemporal_store(v, &out[i]);        // streaming output, no reuse
}

extern "C" void kernel_launch(void* const* d_in, const int* in_sizes, int n_in,
                              void* d_out, int out_size, void* d_ws, size_t ws_size,
                              hipStream_t stream) {
    const fvec4* ev = (const fvec4*)d_in[0];
    unsigned int* bits = (unsigned int*)d_ws;
    int n_events = in_sizes[0] / 4;        // 16,000,000
    int n4 = out_size / 4;                 // 719,680

    hipMemsetAsync(bits, 0, NWORDS * sizeof(unsigned int), stream);
    scatter_bits<<<(n_events + 255) / 256, 256, 0, stream>>>(ev, bits, n_events);
    expand_bits<<<(n4 + 255) / 256, 256, 0, stream>>>(bits, (fvec4*)d_out, n4);
}

// Round 5
// 458.352 us; speedup vs baseline: 1.9483x; 1.9483x over previous
//
#include <hip/hip_runtime.h>

// Event voxelization (QuantizationLayerBinary):
//   events [N,4] float32 rows (x, y, t, p) -> vox[2*C*H*W] set-to-1.0 scatter.
//   C=16, H=260, W=346. bin = ceil(t*C)-1, p in {-1,1} -> {0,1}.
//
// R1: float scatter into 11.5 MB out -> 548 MB HBM writes (no L2 residency).
// R2: byte flags (2.88 MB) -> 788 MB: event READ stream evicts dirty flag lines.
// R3: __builtin_nontemporal_load hint too weak (-18% only, 644 MB).
// R4: check-before-atomicOr -> 3.4x SLOWER (619 us): dependent random probe
//     loads miss L2+L3 (event stream flushes both) and BLOCK at ~900 cyc.
//     Scattered stores are fire-and-forget; scattered loads are poison.
// R5: keep R3's blind byte-store scatter, but load events via buffer_load with
//     CPol SC1|NT (system-scope non-temporal) so the 256 MB stream does NOT
//     allocate in per-XCD L2 -> flag lines stay resident -> writeback ~23 MB.

#define CBINS 16
#define HDIM  260
#define WDIM  346
#define NVOX  (2 * CBINS * HDIM * WDIM)   // 2,878,720

typedef float fvec4 __attribute__((ext_vector_type(4)));
typedef int   ivec4 __attribute__((ext_vector_type(4)));

// CPol bits (gfx940/gfx950 lineage): SC0=0x1, NT=0x2, SC1=0x10.
// SC1|NT = system-scope non-temporal: bypass/no-allocate in per-XCD L2.
#define EV_AUX 0x12

__global__ __launch_bounds__(256) void scatter_flags(const float* __restrict__ ev_base,
                                                     unsigned char* __restrict__ flags,
                                                     int n) {
    int i = blockIdx.x * blockDim.x + threadIdx.x;
    if (i >= n) return;
#if __has_builtin(__builtin_amdgcn_make_buffer_rsrc) && __has_builtin(__builtin_amdgcn_raw_buffer_load_b128)
    __amdgpu_buffer_rsrc_t rsrc = __builtin_amdgcn_make_buffer_rsrc(
        (void*)ev_base, (short)0, n * 16, 0x00020000);   // raw SRD, num_records=bytes
    ivec4 raw = __builtin_amdgcn_raw_buffer_load_b128(rsrc, i * 16, 0, EV_AUX);
    fvec4 e = __builtin_bit_cast(fvec4, raw);            // x, y, t, p
#else
    fvec4 e = __builtin_nontemporal_load((const fvec4*)ev_base + i);
#endif
    float t = e.z;
    if (t > 0.f && t <= 1.f) {
        int xi  = (int)e.x;
        int yi  = (int)e.y;
        int pi  = (e.w > 0.f) ? 1 : 0;     // (p_raw+1)*0.5 with p_raw in {-1,1}
        int bin = (int)ceilf(t * (float)CBINS) - 1;   // in [0,15] given valid t
        int idx = xi + WDIM * yi + WDIM * HDIM * (bin + CBINS * pi);
        flags[idx] = 1;                    // blind store; benign race (all write 1)
    }
}

// Expand 4 flag bytes -> 4 floats per thread (writes ALL of d_out, incl. zeros).
__global__ __launch_bounds__(256) void expand_flags(const uchar4* __restrict__ flags,
                                                    fvec4* __restrict__ out, int n4) {
    int i = blockIdx.x * blockDim.x + threadIdx.x;
    if (i >= n4) return;
    uchar4 f = flags[i];
    fvec4 v = { f.x ? 1.f : 0.f, f.y ? 1.f : 0.f,
                f.z ? 1.f : 0.f, f.w ? 1.f : 0.f };
    __builtin_nontemporal_store(v, &out[i]);        // streaming output, no reuse
}

extern "C" void kernel_launch(void* const* d_in, const int* in_sizes, int n_in,
                              void* d_out, int out_size, void* d_ws, size_t ws_size,
                              hipStream_t stream) {
    const float* ev = (const float*)d_in[0];
    unsigned char* flags = (unsigned char*)d_ws;
    int n_events = in_sizes[0] / 4;        // 16,000,000
    int n4 = out_size / 4;                 // 719,680

    hipMemsetAsync(flags, 0, NVOX, stream);                    // zero flag array
    scatter_flags<<<(n_events + 255) / 256, 256, 0, stream>>>(ev, flags, n_events);
    expand_flags<<<(n4 + 255) / 256, 256, 0, stream>>>((const uchar4*)flags,
                                                       (fvec4*)d_out, n4);
}